// Round 1
// baseline (6215.617 us; speedup 1.0000x reference)
//
#include <hip/hip_runtime.h>
#include <math.h>

#define BB     4
#define LLEN   409
#define DMODEL 192
#define DINNER 384
#define DSTATE 16
#define DRANK  12
#define KCONV  4
#define NLAYER 24
#define NROW   (BB*LLEN)      /* 1636 */
#define EPSF   1e-5f

__device__ __forceinline__ float siluf(float x){ return x/(1.f+__expf(-x)); }
__device__ __forceinline__ float softplusf(float x){ return (x>20.f)? x : log1pf(__expf(x)); }

// ---------------- prep kernels ----------------
__global__ void k_init(const float* __restrict__ t, float* __restrict__ r, int n){
  int i = blockIdx.x*256+threadIdx.x;
  if (i<n) r[i]=t[i];
}

// dst[l][c][r] = src[l][r][c]
__global__ void k_transpose(const float* __restrict__ src, float* __restrict__ dst, int R, int C){
  int total = NLAYER*R*C;
  for (int i = blockIdx.x*blockDim.x+threadIdx.x; i<total; i += gridDim.x*blockDim.x){
    int l = i/(R*C); int rem = i%(R*C); int r = rem/C; int c = rem%C;
    dst[((size_t)l*C + c)*R + r] = src[i];
  }
}

__global__ void k_negexp(const float* __restrict__ a, float* __restrict__ o, int n){
  int i = blockIdx.x*256+threadIdx.x;
  if (i<n) o[i] = -expf(a[i]);
}

// ---------------- layer kernels ----------------
// fused: residual read -> RMSNorm -> in_proj GEMM -> xz  (grid: (ceil(NROW/16), 3))
__global__ __launch_bounds__(256) void k_norm_inproj(const float* __restrict__ residual,
    const float* __restrict__ norm_w,   // layer-offset [DMODEL]
    const float* __restrict__ Wt,       // layer-offset [DMODEL][768]
    float* __restrict__ xz){
  __shared__ __align__(16) float a_lds[DMODEL*20];
  __shared__ float rowscale[16];
  int tid = threadIdx.x;
  int r0  = blockIdx.x*16;
  #pragma unroll
  for (int s=0;s<12;s++){
    int idx = tid + s*256;
    int i = idx/DMODEL, k = idx%DMODEL;
    int row = r0+i;
    float v = (row<NROW) ? residual[(size_t)row*DMODEL+k] : 0.f;
    a_lds[k*20+i] = v;
  }
  __syncthreads();
  int wv = tid>>6, lane = tid&63;
  #pragma unroll
  for (int ii=0; ii<4; ii++){
    int i = wv*4+ii;
    float s = 0.f;
    #pragma unroll
    for (int q=0;q<3;q++){ float v = a_lds[(lane+q*64)*20+i]; s += v*v; }
    #pragma unroll
    for (int off=1; off<64; off<<=1) s += __shfl_xor(s, off, 64);
    if (lane==0) rowscale[i] = rsqrtf(s/(float)DMODEL + EPSF);
  }
  __syncthreads();
  #pragma unroll
  for (int s=0;s<12;s++){
    int idx = tid + s*256;
    int i = idx/DMODEL, k = idx%DMODEL;
    a_lds[k*20+i] *= rowscale[i]*norm_w[k];
  }
  __syncthreads();
  int j = blockIdx.y*256 + tid;   // < 768
  float acc[16];
  #pragma unroll
  for (int i=0;i<16;i++) acc[i]=0.f;
  for (int k=0;k<DMODEL;k++){
    float w = Wt[(size_t)k*768 + j];
    const float4* ar = reinterpret_cast<const float4*>(&a_lds[k*20]);
    #pragma unroll
    for (int q=0;q<4;q++){
      float4 a = ar[q];
      acc[q*4+0]+=a.x*w; acc[q*4+1]+=a.y*w; acc[q*4+2]+=a.z*w; acc[q*4+3]+=a.w*w;
    }
  }
  #pragma unroll
  for (int i=0;i<16;i++){
    int row=r0+i;
    if(row<NROW) xz[(size_t)row*768 + j] = acc[i];
  }
}

// causal depthwise conv + bias + silu; dir 0 = fwd, dir 1 = bwd (flipped coords)
__global__ __launch_bounds__(256) void k_conv(const float* __restrict__ xz,
    const float* __restrict__ cwf, const float* __restrict__ cbf,
    const float* __restrict__ cwb, const float* __restrict__ cbb,
    float* __restrict__ xf_f, float* __restrict__ xf_b){
  int idx = blockIdx.x*256 + threadIdx.x;
  if (idx >= NROW*DINNER) return;
  int d = idx % DINNER; int bl = idx / DINNER; int b = bl / LLEN; int l = bl % LLEN;
  int dir = blockIdx.y;
  const float* w = (dir? cwb : cwf) + d*KCONV;
  float acc = (dir? cbb : cbf)[d];
  if (dir==0){
    #pragma unroll
    for (int k=0;k<KCONV;k++){
      int o = l-3+k;
      if (o>=0) acc += w[k]*xz[((size_t)(b*LLEN+o))*768 + d];
    }
  } else {
    #pragma unroll
    for (int k=0;k<KCONV;k++){
      if (l+k>=3) acc += w[k]*xz[((size_t)(b*LLEN+(LLEN-1-l-k+3)))*768 + d];
    }
  }
  float* out = dir? xf_b : xf_f;
  out[(size_t)bl*DINNER + d] = siluf(acc);
}

// fused: x_proj GEMM (-> dtbc) + dt_proj + softplus (-> dt); grid (ceil(NROW/16),1,2)
__global__ __launch_bounds__(256) void k_xp(
    const float* __restrict__ xf_f, const float* __restrict__ xf_b,
    const float* __restrict__ WxpF, const float* __restrict__ WxpB,
    const float* __restrict__ WdtF, const float* __restrict__ WdtB,
    const float* __restrict__ dtbF, const float* __restrict__ dtbB,
    float* __restrict__ dtbc_f, float* __restrict__ dtbc_b,
    float* __restrict__ dt_f, float* __restrict__ dt_b){
  __shared__ __align__(16) float a_lds[DINNER*20];
  __shared__ float dtin[16*12];
  int dir = blockIdx.z;
  const float* xf  = dir? xf_b : xf_f;
  const float* Wxp = dir? WxpB : WxpF;
  const float* Wdt = dir? WdtB : WdtF;
  const float* dtb = dir? dtbB : dtbF;
  float* dtbc = dir? dtbc_b : dtbc_f;
  float* dtp  = dir? dt_b  : dt_f;
  int tid = threadIdx.x; int r0 = blockIdx.x*16;
  #pragma unroll
  for (int s=0;s<24;s++){
    int idx = tid + s*256; int i = idx/DINNER, k = idx%DINNER; int row=r0+i;
    a_lds[k*20+i] = (row<NROW)? xf[(size_t)row*DINNER + k] : 0.f;
  }
  __syncthreads();
  int j = tid & 63; int rg = tid >> 6;     // rows rg*4 .. rg*4+3
  float acc[4] = {0.f,0.f,0.f,0.f};
  for (int k=0;k<DINNER;k++){
    float w = (j<44)? Wxp[(size_t)k*44 + j] : 0.f;
    float4 a = *reinterpret_cast<const float4*>(&a_lds[k*20 + rg*4]);
    acc[0]+=a.x*w; acc[1]+=a.y*w; acc[2]+=a.z*w; acc[3]+=a.w*w;
  }
  #pragma unroll
  for (int s2=0;s2<4;s2++){
    int i = rg*4+s2; int row = r0 + i;
    if (j<44 && row<NROW) dtbc[(size_t)row*44 + j] = acc[s2];
    if (j<12) dtin[i*12 + j] = acc[s2];
  }
  __syncthreads();
  #pragma unroll
  for (int s=0;s<24;s++){
    int o = tid + s*256; int i = o/DINNER, dd = o%DINNER; int row = r0+i;
    float a = dtb[dd];
    #pragma unroll
    for (int r=0;r<12;r++) a += dtin[i*12+r]*Wdt[(size_t)r*DINNER+dd];
    if (row<NROW) dtp[(size_t)row*DINNER+dd] = softplusf(a);
  }
}

// selective scan; grid (DINNER/16, BB, 2); 1 thread per (d,n) state
__global__ __launch_bounds__(256) void k_scan(
    const float* __restrict__ xf_f, const float* __restrict__ xf_b,
    const float* __restrict__ dtbc_f, const float* __restrict__ dtbc_b,
    const float* __restrict__ dt_f, const float* __restrict__ dt_b,
    const float* __restrict__ anF, const float* __restrict__ anB,
    const float* __restrict__ DpF, const float* __restrict__ DpB,
    float* __restrict__ y_fo, float* __restrict__ y_bo){
  int dir = blockIdx.z;
  const float* xf   = dir? xf_b  : xf_f;
  const float* dtbc = dir? dtbc_b: dtbc_f;
  const float* dtp  = dir? dt_b  : dt_f;
  const float* an   = dir? anB   : anF;
  const float* Dp   = dir? DpB   : DpF;
  float* y = dir? y_bo : y_fo;
  int b = blockIdx.y;
  int dl = threadIdx.x>>4, n = threadIdx.x&15;
  int d = blockIdx.x*16 + dl;
  float A  = an[d*DSTATE+n];
  float Dd = Dp[d];
  size_t base = (size_t)b*LLEN;
  float h = 0.f;
  float dtv = dtp[base*DINNER+d];
  float u   = xf [base*DINNER+d];
  float Bn  = dtbc[base*44+12+n];
  float Cn  = dtbc[base*44+28+n];
  for (int t=0;t<LLEN;t++){
    float dtv2=0.f,u2=0.f,Bn2=0.f,Cn2=0.f;
    if (t+1<LLEN){
      size_t r2 = base+t+1;
      dtv2 = dtp[r2*DINNER+d]; u2 = xf[r2*DINNER+d];
      Bn2 = dtbc[r2*44+12+n];  Cn2 = dtbc[r2*44+28+n];
    }
    h = h*__expf(dtv*A) + (dtv*u)*Bn;
    float p = h*Cn;
    p += __shfl_xor(p,1,64); p += __shfl_xor(p,2,64);
    p += __shfl_xor(p,4,64); p += __shfl_xor(p,8,64);
    if (n==0) y[(base+t)*DINNER+d] = p + u*Dd;
    dtv=dtv2; u=u2; Bn=Bn2; Cn=Cn2;
  }
}

// fused: gate + out_proj GEMM; residual += result; grid (ceil(NROW/16))
__global__ __launch_bounds__(256) void k_out(
    const float* __restrict__ y_f, const float* __restrict__ y_b,
    const float* __restrict__ xz, const float* __restrict__ Wt,
    float* __restrict__ residual){
  __shared__ __align__(16) float a_lds[DINNER*20];
  int tid = threadIdx.x; int r0 = blockIdx.x*16;
  #pragma unroll
  for (int s=0;s<24;s++){
    int idx = tid + s*256; int i = idx/DINNER, k = idx%DINNER; int row=r0+i;
    float v = 0.f;
    if (row<NROW){
      int b = row/LLEN, l = row%LLEN;
      float yf = y_f[(size_t)row*DINNER+k];
      float yb = y_b[((size_t)(b*LLEN+(LLEN-1-l)))*DINNER+k];
      float z  = xz[(size_t)row*768 + DINNER + k];
      v = (yf+yb)*siluf(z)*0.5f;
    }
    a_lds[k*20+i] = v;
  }
  __syncthreads();
  int j = tid;
  if (j < DMODEL){
    float acc[16];
    #pragma unroll
    for (int i=0;i<16;i++) acc[i]=0.f;
    for (int k=0;k<DINNER;k++){
      float w = Wt[(size_t)k*DMODEL + j];
      const float4* ar = reinterpret_cast<const float4*>(&a_lds[k*20]);
      #pragma unroll
      for (int q=0;q<4;q++){
        float4 a = ar[q];
        acc[q*4+0]+=a.x*w; acc[q*4+1]+=a.y*w; acc[q*4+2]+=a.z*w; acc[q*4+3]+=a.w*w;
      }
    }
    #pragma unroll
    for (int i=0;i<16;i++){
      int row=r0+i;
      if(row<NROW) residual[(size_t)row*DMODEL + j] += acc[i];
    }
  }
}

// final RMSNorm -> d_out; grid(ceil(NROW/4)); one wave per row
__global__ __launch_bounds__(256) void k_final(const float* __restrict__ residual,
    const float* __restrict__ nfw, float* __restrict__ out){
  int wv = threadIdx.x>>6, lane = threadIdx.x&63;
  int row = blockIdx.x*4 + wv;
  if (row >= NROW) return;
  float v[3]; float s = 0.f;
  #pragma unroll
  for (int q=0;q<3;q++){ v[q] = residual[(size_t)row*DMODEL + lane + q*64]; s += v[q]*v[q]; }
  #pragma unroll
  for (int off=1; off<64; off<<=1) s += __shfl_xor(s, off, 64);
  float sc = rsqrtf(s/(float)DMODEL + EPSF);
  #pragma unroll
  for (int q=0;q<3;q++) out[(size_t)row*DMODEL + lane + q*64] = v[q]*sc*nfw[lane + q*64];
}

// ---------------- host ----------------
extern "C" void kernel_launch(void* const* d_in, const int* in_sizes, int n_in,
                              void* d_out, int out_size, void* d_ws, size_t ws_size,
                              hipStream_t stream){
  const float* tokens     = (const float*)d_in[0];
  const float* norm_w     = (const float*)d_in[1];
  const float* in_proj_w  = (const float*)d_in[2];
  const float* conv_w     = (const float*)d_in[3];
  const float* conv_b     = (const float*)d_in[4];
  const float* conv_w_b   = (const float*)d_in[5];
  const float* conv_b_b   = (const float*)d_in[6];
  const float* x_proj_w   = (const float*)d_in[7];
  const float* x_proj_w_b = (const float*)d_in[8];
  const float* dt_proj_w  = (const float*)d_in[9];
  const float* dt_bias    = (const float*)d_in[10];
  const float* dt_proj_w_b= (const float*)d_in[11];
  const float* dt_bias_b  = (const float*)d_in[12];
  const float* A_log      = (const float*)d_in[13];
  const float* A_log_b    = (const float*)d_in[14];
  const float* D_param    = (const float*)d_in[15];
  const float* D_param_b  = (const float*)d_in[16];
  const float* out_proj_w = (const float*)d_in[17];
  const float* norm_f_w   = (const float*)d_in[18];

  float* ws = (float*)d_ws;
  size_t off = 0;
  float* residual = ws + off; off += (size_t)NROW*DMODEL;
  float* xz       = ws + off; off += (size_t)NROW*768;
  float* xf_f     = ws + off; off += (size_t)NROW*DINNER;
  float* xf_b     = ws + off; off += (size_t)NROW*DINNER;
  float* dtbc_f   = ws + off; off += (size_t)NROW*44;
  float* dtbc_b   = ws + off; off += (size_t)NROW*44;
  float* dt_f     = ws + off; off += (size_t)NROW*DINNER;
  float* dt_b     = ws + off; off += (size_t)NROW*DINNER;
  float* y_f      = ws + off; off += (size_t)NROW*DINNER;
  float* y_b      = ws + off; off += (size_t)NROW*DINNER;
  float* WtIn     = ws + off; off += (size_t)NLAYER*DMODEL*768;
  float* WtXpF    = ws + off; off += (size_t)NLAYER*DINNER*44;
  float* WtXpB    = ws + off; off += (size_t)NLAYER*DINNER*44;
  float* WtDtF    = ws + off; off += (size_t)NLAYER*DRANK*DINNER;
  float* WtDtB    = ws + off; off += (size_t)NLAYER*DRANK*DINNER;
  float* WtOut    = ws + off; off += (size_t)NLAYER*DINNER*DMODEL;
  float* AnF      = ws + off; off += (size_t)NLAYER*DINNER*DSTATE;
  float* AnB      = ws + off; off += (size_t)NLAYER*DINNER*DSTATE;
  if (off*sizeof(float) > ws_size) return;   // workspace too small: fail loudly

  // prep
  k_init<<<dim3((NROW*DMODEL+255)/256),256,0,stream>>>(tokens, residual, NROW*DMODEL);
  k_transpose<<<2048,256,0,stream>>>(in_proj_w,  WtIn,  768, DMODEL);
  k_transpose<<<1024,256,0,stream>>>(x_proj_w,   WtXpF, 44,  DINNER);
  k_transpose<<<1024,256,0,stream>>>(x_proj_w_b, WtXpB, 44,  DINNER);
  k_transpose<<<512, 256,0,stream>>>(dt_proj_w,  WtDtF, DINNER, DRANK);
  k_transpose<<<512, 256,0,stream>>>(dt_proj_w_b,WtDtB, DINNER, DRANK);
  k_transpose<<<2048,256,0,stream>>>(out_proj_w, WtOut, DMODEL, DINNER);
  k_negexp<<<dim3((NLAYER*DINNER*DSTATE+255)/256),256,0,stream>>>(A_log,   AnF, NLAYER*DINNER*DSTATE);
  k_negexp<<<dim3((NLAYER*DINNER*DSTATE+255)/256),256,0,stream>>>(A_log_b, AnB, NLAYER*DINNER*DSTATE);

  const int RT = (NROW+15)/16;   // 103 row tiles
  for (int l=0; l<NLAYER; l++){
    k_norm_inproj<<<dim3(RT,3),256,0,stream>>>(residual, norm_w + (size_t)l*DMODEL,
        WtIn + (size_t)l*DMODEL*768, xz);
    k_conv<<<dim3((NROW*DINNER+255)/256,2),256,0,stream>>>(xz,
        conv_w + (size_t)l*DINNER*KCONV, conv_b + (size_t)l*DINNER,
        conv_w_b + (size_t)l*DINNER*KCONV, conv_b_b + (size_t)l*DINNER, xf_f, xf_b);
    k_xp<<<dim3(RT,1,2),256,0,stream>>>(xf_f, xf_b,
        WtXpF + (size_t)l*DINNER*44, WtXpB + (size_t)l*DINNER*44,
        WtDtF + (size_t)l*DRANK*DINNER, WtDtB + (size_t)l*DRANK*DINNER,
        dt_bias + (size_t)l*DINNER, dt_bias_b + (size_t)l*DINNER,
        dtbc_f, dtbc_b, dt_f, dt_b);
    k_scan<<<dim3(DINNER/16,BB,2),256,0,stream>>>(xf_f, xf_b, dtbc_f, dtbc_b, dt_f, dt_b,
        AnF + (size_t)l*DINNER*DSTATE, AnB + (size_t)l*DINNER*DSTATE,
        D_param + (size_t)l*DINNER, D_param_b + (size_t)l*DINNER, y_f, y_b);
    k_out<<<dim3(RT),256,0,stream>>>(y_f, y_b, xz, WtOut + (size_t)l*DINNER*DMODEL, residual);
  }
  k_final<<<dim3((NROW+3)/4),256,0,stream>>>(residual, norm_f_w, (float*)d_out);
}

// Round 2
// 3992.514 us; speedup vs baseline: 1.5568x; 1.5568x over previous
//
#include <hip/hip_runtime.h>
#include <math.h>

#define BB     4
#define LLEN   409
#define DMODEL 192
#define DINNER 384
#define DSTATE 16
#define DRANK  12
#define KCONV  4
#define NLAYER 24
#define NROW   (BB*LLEN)      /* 1636 */
#define EPSF   1e-5f
#define CHUNK  26             /* scan chunk length */
#define NCH    16             /* chunks per sequence: 16*26=416 >= 409 */

__device__ __forceinline__ float siluf(float x){ return x/(1.f+__expf(-x)); }
__device__ __forceinline__ float softplusf(float x){ return (x>20.f)? x : log1pf(__expf(x)); }

// ---------------- prep kernels ----------------
__global__ void k_init(const float* __restrict__ t, float* __restrict__ r, int n){
  int i = blockIdx.x*256+threadIdx.x;
  if (i<n) r[i]=t[i];
}

// dst[l][c][r] = src[l][r][c]
__global__ void k_transpose(const float* __restrict__ src, float* __restrict__ dst, int R, int C){
  int total = NLAYER*R*C;
  for (int i = blockIdx.x*blockDim.x+threadIdx.x; i<total; i += gridDim.x*blockDim.x){
    int l = i/(R*C); int rem = i%(R*C); int r = rem/C; int c = rem%C;
    dst[((size_t)l*C + c)*R + r] = src[i];
  }
}

__global__ void k_negexp(const float* __restrict__ a, float* __restrict__ o, int n){
  int i = blockIdx.x*256+threadIdx.x;
  if (i<n) o[i] = -expf(a[i]);
}

// ---------------- layer kernels ----------------
// fused: residual read -> RMSNorm -> in_proj GEMM -> xz  (grid: (ceil(NROW/16), 3))
__global__ __launch_bounds__(256) void k_norm_inproj(const float* __restrict__ residual,
    const float* __restrict__ norm_w,   // layer-offset [DMODEL]
    const float* __restrict__ Wt,       // layer-offset [DMODEL][768]
    float* __restrict__ xz){
  __shared__ __align__(16) float a_lds[DMODEL*20];
  __shared__ float rowscale[16];
  int tid = threadIdx.x;
  int r0  = blockIdx.x*16;
  #pragma unroll
  for (int s=0;s<12;s++){
    int idx = tid + s*256;
    int i = idx/DMODEL, k = idx%DMODEL;
    int row = r0+i;
    float v = (row<NROW) ? residual[(size_t)row*DMODEL+k] : 0.f;
    a_lds[k*20+i] = v;
  }
  __syncthreads();
  int wv = tid>>6, lane = tid&63;
  #pragma unroll
  for (int ii=0; ii<4; ii++){
    int i = wv*4+ii;
    float s = 0.f;
    #pragma unroll
    for (int q=0;q<3;q++){ float v = a_lds[(lane+q*64)*20+i]; s += v*v; }
    #pragma unroll
    for (int off=1; off<64; off<<=1) s += __shfl_xor(s, off, 64);
    if (lane==0) rowscale[i] = rsqrtf(s/(float)DMODEL + EPSF);
  }
  __syncthreads();
  #pragma unroll
  for (int s=0;s<12;s++){
    int idx = tid + s*256;
    int i = idx/DMODEL, k = idx%DMODEL;
    a_lds[k*20+i] *= rowscale[i]*norm_w[k];
  }
  __syncthreads();
  int j = blockIdx.y*256 + tid;   // < 768
  float acc[16];
  #pragma unroll
  for (int i=0;i<16;i++) acc[i]=0.f;
  for (int k=0;k<DMODEL;k++){
    float w = Wt[(size_t)k*768 + j];
    const float4* ar = reinterpret_cast<const float4*>(&a_lds[k*20]);
    #pragma unroll
    for (int q=0;q<4;q++){
      float4 a = ar[q];
      acc[q*4+0]+=a.x*w; acc[q*4+1]+=a.y*w; acc[q*4+2]+=a.z*w; acc[q*4+3]+=a.w*w;
    }
  }
  #pragma unroll
  for (int i=0;i<16;i++){
    int row=r0+i;
    if(row<NROW) xz[(size_t)row*768 + j] = acc[i];
  }
}

// causal depthwise conv + bias + silu; dir 0 = fwd, dir 1 = bwd (flipped coords)
__global__ __launch_bounds__(256) void k_conv(const float* __restrict__ xz,
    const float* __restrict__ cwf, const float* __restrict__ cbf,
    const float* __restrict__ cwb, const float* __restrict__ cbb,
    float* __restrict__ xf_f, float* __restrict__ xf_b){
  int idx = blockIdx.x*256 + threadIdx.x;
  if (idx >= NROW*DINNER) return;
  int d = idx % DINNER; int bl = idx / DINNER; int b = bl / LLEN; int l = bl % LLEN;
  int dir = blockIdx.y;
  const float* w = (dir? cwb : cwf) + d*KCONV;
  float acc = (dir? cbb : cbf)[d];
  if (dir==0){
    #pragma unroll
    for (int k=0;k<KCONV;k++){
      int o = l-3+k;
      if (o>=0) acc += w[k]*xz[((size_t)(b*LLEN+o))*768 + d];
    }
  } else {
    #pragma unroll
    for (int k=0;k<KCONV;k++){
      if (l+k>=3) acc += w[k]*xz[((size_t)(b*LLEN+(LLEN-1-l-k+3)))*768 + d];
    }
  }
  float* out = dir? xf_b : xf_f;
  out[(size_t)bl*DINNER + d] = siluf(acc);
}

// fused: x_proj GEMM (-> dtbc) + dt_proj + softplus (-> dt); grid (ceil(NROW/16),1,2)
__global__ __launch_bounds__(256) void k_xp(
    const float* __restrict__ xf_f, const float* __restrict__ xf_b,
    const float* __restrict__ WxpF, const float* __restrict__ WxpB,
    const float* __restrict__ WdtF, const float* __restrict__ WdtB,
    const float* __restrict__ dtbF, const float* __restrict__ dtbB,
    float* __restrict__ dtbc_f, float* __restrict__ dtbc_b,
    float* __restrict__ dt_f, float* __restrict__ dt_b){
  __shared__ __align__(16) float a_lds[DINNER*20];
  __shared__ float dtin[16*12];
  int dir = blockIdx.z;
  const float* xf  = dir? xf_b : xf_f;
  const float* Wxp = dir? WxpB : WxpF;
  const float* Wdt = dir? WdtB : WdtF;
  const float* dtb = dir? dtbB : dtbF;
  float* dtbc = dir? dtbc_b : dtbc_f;
  float* dtp  = dir? dt_b  : dt_f;
  int tid = threadIdx.x; int r0 = blockIdx.x*16;
  #pragma unroll
  for (int s=0;s<24;s++){
    int idx = tid + s*256; int i = idx/DINNER, k = idx%DINNER; int row=r0+i;
    a_lds[k*20+i] = (row<NROW)? xf[(size_t)row*DINNER + k] : 0.f;
  }
  __syncthreads();
  int j = tid & 63; int rg = tid >> 6;     // rows rg*4 .. rg*4+3
  float acc[4] = {0.f,0.f,0.f,0.f};
  for (int k=0;k<DINNER;k++){
    float w = (j<44)? Wxp[(size_t)k*44 + j] : 0.f;
    float4 a = *reinterpret_cast<const float4*>(&a_lds[k*20 + rg*4]);
    acc[0]+=a.x*w; acc[1]+=a.y*w; acc[2]+=a.z*w; acc[3]+=a.w*w;
  }
  #pragma unroll
  for (int s2=0;s2<4;s2++){
    int i = rg*4+s2; int row = r0 + i;
    if (j<44 && row<NROW) dtbc[(size_t)row*44 + j] = acc[s2];
    if (j<12) dtin[i*12 + j] = acc[s2];
  }
  __syncthreads();
  #pragma unroll
  for (int s=0;s<24;s++){
    int o = tid + s*256; int i = o/DINNER, dd = o%DINNER; int row = r0+i;
    float a = dtb[dd];
    #pragma unroll
    for (int r=0;r<12;r++) a += dtin[i*12+r]*Wdt[(size_t)r*DINNER+dd];
    if (row<NROW) dtp[(size_t)row*DINNER+dd] = softplusf(a);
  }
}

// -------- chunked selective scan --------
// pass 1: per-chunk transfer fn (q = h_end from h0=0, sdt = sum dt)
// grid (DINNER/16, BB*NCH, 2), 256 threads = 16 d x 16 n
__global__ __launch_bounds__(256) void k_scan1(
    const float* __restrict__ xf_f, const float* __restrict__ xf_b,
    const float* __restrict__ dtbc_f, const float* __restrict__ dtbc_b,
    const float* __restrict__ dt_f, const float* __restrict__ dt_b,
    const float* __restrict__ anF, const float* __restrict__ anB,
    float* __restrict__ q_buf, float* __restrict__ sdt_buf){
  int dir = blockIdx.z;
  int b  = blockIdx.y >> 4;
  int ch = blockIdx.y & 15;
  if (ch == NCH-1) return;               // last chunk's transfer fn is never used
  const float* xf   = dir? xf_b  : xf_f;
  const float* dtbc = dir? dtbc_b: dtbc_f;
  const float* dtp  = dir? dt_b  : dt_f;
  const float* an   = dir? anB   : anF;
  int t0 = ch*CHUNK;                     // ch<15 -> full 26 steps
  int d0 = blockIdx.x*16;
  size_t base = (size_t)b*LLEN + t0;
  __shared__ float dt_s[CHUNK*16], u_s[CHUNK*16], B_s[CHUNK*16];
  int tid = threadIdx.x;
  for (int idx = tid; idx < CHUNK*16; idx += 256){
    int t = idx>>4, dd = idx&15;
    size_t r = base + t;
    dt_s[idx] = dtp[r*DINNER + d0 + dd];
    u_s[idx]  = xf [r*DINNER + d0 + dd];
    B_s[idx]  = dtbc[r*44 + 12 + dd];
  }
  __syncthreads();
  int dl = tid>>4, n = tid&15;
  int d = d0 + dl;
  float A = an[d*DSTATE+n];
  float h = 0.f, sdt = 0.f;
  #pragma unroll
  for (int t=0;t<CHUNK;t++){
    float dtv = dt_s[t*16+dl];
    float u   = u_s [t*16+dl];
    float Bn  = B_s [t*16+n];
    h = h*__expf(dtv*A) + (dtv*u)*Bn;
    sdt += dtv;
  }
  size_t ci = (((size_t)dir*BB + b)*NCH + ch);
  q_buf[(ci*DINNER + d)*DSTATE + n] = h;
  if (n==0) sdt_buf[ci*DINNER + d] = sdt;
}

// pass 2: fold carries from preceding chunks, replay chunk, emit y
// grid (DINNER/16, BB*NCH, 2), 256 threads
__global__ __launch_bounds__(256) void k_scan2(
    const float* __restrict__ xf_f, const float* __restrict__ xf_b,
    const float* __restrict__ dtbc_f, const float* __restrict__ dtbc_b,
    const float* __restrict__ dt_f, const float* __restrict__ dt_b,
    const float* __restrict__ anF, const float* __restrict__ anB,
    const float* __restrict__ DpF, const float* __restrict__ DpB,
    const float* __restrict__ q_buf, const float* __restrict__ sdt_buf,
    float* __restrict__ y_fo, float* __restrict__ y_bo){
  int dir = blockIdx.z;
  int b  = blockIdx.y >> 4;
  int ch = blockIdx.y & 15;
  const float* xf   = dir? xf_b  : xf_f;
  const float* dtbc = dir? dtbc_b: dtbc_f;
  const float* dtp  = dir? dt_b  : dt_f;
  const float* an   = dir? anB   : anF;
  const float* Dp   = dir? DpB   : DpF;
  float* y = dir? y_bo : y_fo;
  int t0 = ch*CHUNK;
  int T  = (t0+CHUNK<=LLEN)? CHUNK : (LLEN-t0);   // 26, last chunk 19
  int d0 = blockIdx.x*16;
  size_t base = (size_t)b*LLEN + t0;
  __shared__ float dt_s[CHUNK*16], u_s[CHUNK*16], B_s[CHUNK*16], C_s[CHUNK*16], y_s[CHUNK*16];
  int tid = threadIdx.x;
  for (int idx = tid; idx < T*16; idx += 256){
    int t = idx>>4, dd = idx&15;
    size_t r = base + t;
    dt_s[idx] = dtp[r*DINNER + d0 + dd];
    u_s[idx]  = xf [r*DINNER + d0 + dd];
    B_s[idx]  = dtbc[r*44 + 12 + dd];
    C_s[idx]  = dtbc[r*44 + 28 + dd];
  }
  __syncthreads();
  int dl = tid>>4, n = tid&15;
  int d = d0 + dl;
  float A  = an[d*DSTATE+n];
  float Dd = Dp[d];
  // carry-in: fold preceding chunks' transfer functions
  float h = 0.f;
  size_t sbase = ((size_t)dir*BB + b)*NCH;
  for (int cc=0; cc<ch; cc++){
    float P = __expf(A * sdt_buf[(sbase+cc)*DINNER + d]);
    h = q_buf[((sbase+cc)*DINNER + d)*DSTATE + n] + P*h;
  }
  for (int t=0;t<T;t++){
    float dtv = dt_s[t*16+dl];
    float u   = u_s [t*16+dl];
    float Bn  = B_s [t*16+n];
    float Cn  = C_s [t*16+n];
    h = h*__expf(dtv*A) + (dtv*u)*Bn;
    float p = h*Cn;
    p += __shfl_xor(p,1,64); p += __shfl_xor(p,2,64);
    p += __shfl_xor(p,4,64); p += __shfl_xor(p,8,64);
    if (n==0) y_s[t*16+dl] = p + u*Dd;
  }
  __syncthreads();
  for (int idx = tid; idx < T*16; idx += 256){
    int t = idx>>4, dd = idx&15;
    y[(base+t)*DINNER + d0 + dd] = y_s[idx];
  }
}

// fused: gate + out_proj GEMM; residual += result; grid (ceil(NROW/16))
__global__ __launch_bounds__(256) void k_out(
    const float* __restrict__ y_f, const float* __restrict__ y_b,
    const float* __restrict__ xz, const float* __restrict__ Wt,
    float* __restrict__ residual){
  __shared__ __align__(16) float a_lds[DINNER*20];
  int tid = threadIdx.x; int r0 = blockIdx.x*16;
  #pragma unroll
  for (int s=0;s<24;s++){
    int idx = tid + s*256; int i = idx/DINNER, k = idx%DINNER; int row=r0+i;
    float v = 0.f;
    if (row<NROW){
      int b = row/LLEN, l = row%LLEN;
      float yf = y_f[(size_t)row*DINNER+k];
      float yb = y_b[((size_t)(b*LLEN+(LLEN-1-l)))*DINNER+k];
      float z  = xz[(size_t)row*768 + DINNER + k];
      v = (yf+yb)*siluf(z)*0.5f;
    }
    a_lds[k*20+i] = v;
  }
  __syncthreads();
  int j = tid;
  if (j < DMODEL){
    float acc[16];
    #pragma unroll
    for (int i=0;i<16;i++) acc[i]=0.f;
    for (int k=0;k<DINNER;k++){
      float w = Wt[(size_t)k*DMODEL + j];
      const float4* ar = reinterpret_cast<const float4*>(&a_lds[k*20]);
      #pragma unroll
      for (int q=0;q<4;q++){
        float4 a = ar[q];
        acc[q*4+0]+=a.x*w; acc[q*4+1]+=a.y*w; acc[q*4+2]+=a.z*w; acc[q*4+3]+=a.w*w;
      }
    }
    #pragma unroll
    for (int i=0;i<16;i++){
      int row=r0+i;
      if(row<NROW) residual[(size_t)row*DMODEL + j] += acc[i];
    }
  }
}

// final RMSNorm -> d_out; grid(ceil(NROW/4)); one wave per row
__global__ __launch_bounds__(256) void k_final(const float* __restrict__ residual,
    const float* __restrict__ nfw, float* __restrict__ out){
  int wv = threadIdx.x>>6, lane = threadIdx.x&63;
  int row = blockIdx.x*4 + wv;
  if (row >= NROW) return;
  float v[3]; float s = 0.f;
  #pragma unroll
  for (int q=0;q<3;q++){ v[q] = residual[(size_t)row*DMODEL + lane + q*64]; s += v[q]*v[q]; }
  #pragma unroll
  for (int off=1; off<64; off<<=1) s += __shfl_xor(s, off, 64);
  float sc = rsqrtf(s/(float)DMODEL + EPSF);
  #pragma unroll
  for (int q=0;q<3;q++) out[(size_t)row*DMODEL + lane + q*64] = v[q]*sc*nfw[lane + q*64];
}

// ---------------- host ----------------
extern "C" void kernel_launch(void* const* d_in, const int* in_sizes, int n_in,
                              void* d_out, int out_size, void* d_ws, size_t ws_size,
                              hipStream_t stream){
  const float* tokens     = (const float*)d_in[0];
  const float* norm_w     = (const float*)d_in[1];
  const float* in_proj_w  = (const float*)d_in[2];
  const float* conv_w     = (const float*)d_in[3];
  const float* conv_b     = (const float*)d_in[4];
  const float* conv_w_b   = (const float*)d_in[5];
  const float* conv_b_b   = (const float*)d_in[6];
  const float* x_proj_w   = (const float*)d_in[7];
  const float* x_proj_w_b = (const float*)d_in[8];
  const float* dt_proj_w  = (const float*)d_in[9];
  const float* dt_bias    = (const float*)d_in[10];
  const float* dt_proj_w_b= (const float*)d_in[11];
  const float* dt_bias_b  = (const float*)d_in[12];
  const float* A_log      = (const float*)d_in[13];
  const float* A_log_b    = (const float*)d_in[14];
  const float* D_param    = (const float*)d_in[15];
  const float* D_param_b  = (const float*)d_in[16];
  const float* out_proj_w = (const float*)d_in[17];
  const float* norm_f_w   = (const float*)d_in[18];

  float* ws = (float*)d_ws;
  size_t off = 0;
  float* residual = ws + off; off += (size_t)NROW*DMODEL;
  float* xz       = ws + off; off += (size_t)NROW*768;
  float* xf_f     = ws + off; off += (size_t)NROW*DINNER;
  float* xf_b     = ws + off; off += (size_t)NROW*DINNER;
  float* dtbc_f   = ws + off; off += (size_t)NROW*44;
  float* dtbc_b   = ws + off; off += (size_t)NROW*44;
  float* dt_f     = ws + off; off += (size_t)NROW*DINNER;
  float* dt_b     = ws + off; off += (size_t)NROW*DINNER;
  float* y_f      = ws + off; off += (size_t)NROW*DINNER;
  float* y_b      = ws + off; off += (size_t)NROW*DINNER;
  float* q_buf    = ws + off; off += (size_t)2*BB*NCH*DINNER*DSTATE;
  float* sdt_buf  = ws + off; off += (size_t)2*BB*NCH*DINNER;
  float* WtIn     = ws + off; off += (size_t)NLAYER*DMODEL*768;
  float* WtXpF    = ws + off; off += (size_t)NLAYER*DINNER*44;
  float* WtXpB    = ws + off; off += (size_t)NLAYER*DINNER*44;
  float* WtDtF    = ws + off; off += (size_t)NLAYER*DRANK*DINNER;
  float* WtDtB    = ws + off; off += (size_t)NLAYER*DRANK*DINNER;
  float* WtOut    = ws + off; off += (size_t)NLAYER*DINNER*DMODEL;
  float* AnF      = ws + off; off += (size_t)NLAYER*DINNER*DSTATE;
  float* AnB      = ws + off; off += (size_t)NLAYER*DINNER*DSTATE;
  if (off*sizeof(float) > ws_size) return;   // workspace too small: fail loudly

  // prep
  k_init<<<dim3((NROW*DMODEL+255)/256),256,0,stream>>>(tokens, residual, NROW*DMODEL);
  k_transpose<<<2048,256,0,stream>>>(in_proj_w,  WtIn,  768, DMODEL);
  k_transpose<<<1024,256,0,stream>>>(x_proj_w,   WtXpF, 44,  DINNER);
  k_transpose<<<1024,256,0,stream>>>(x_proj_w_b, WtXpB, 44,  DINNER);
  k_transpose<<<512, 256,0,stream>>>(dt_proj_w,  WtDtF, DINNER, DRANK);
  k_transpose<<<512, 256,0,stream>>>(dt_proj_w_b,WtDtB, DINNER, DRANK);
  k_transpose<<<2048,256,0,stream>>>(out_proj_w, WtOut, DMODEL, DINNER);
  k_negexp<<<dim3((NLAYER*DINNER*DSTATE+255)/256),256,0,stream>>>(A_log,   AnF, NLAYER*DINNER*DSTATE);
  k_negexp<<<dim3((NLAYER*DINNER*DSTATE+255)/256),256,0,stream>>>(A_log_b, AnB, NLAYER*DINNER*DSTATE);

  const int RT = (NROW+15)/16;   // 103 row tiles
  for (int l=0; l<NLAYER; l++){
    k_norm_inproj<<<dim3(RT,3),256,0,stream>>>(residual, norm_w + (size_t)l*DMODEL,
        WtIn + (size_t)l*DMODEL*768, xz);
    k_conv<<<dim3((NROW*DINNER+255)/256,2),256,0,stream>>>(xz,
        conv_w + (size_t)l*DINNER*KCONV, conv_b + (size_t)l*DINNER,
        conv_w_b + (size_t)l*DINNER*KCONV, conv_b_b + (size_t)l*DINNER, xf_f, xf_b);
    k_xp<<<dim3(RT,1,2),256,0,stream>>>(xf_f, xf_b,
        WtXpF + (size_t)l*DINNER*44, WtXpB + (size_t)l*DINNER*44,
        WtDtF + (size_t)l*DRANK*DINNER, WtDtB + (size_t)l*DRANK*DINNER,
        dt_bias + (size_t)l*DINNER, dt_bias_b + (size_t)l*DINNER,
        dtbc_f, dtbc_b, dt_f, dt_b);
    k_scan1<<<dim3(DINNER/16,BB*NCH,2),256,0,stream>>>(xf_f, xf_b, dtbc_f, dtbc_b, dt_f, dt_b,
        AnF + (size_t)l*DINNER*DSTATE, AnB + (size_t)l*DINNER*DSTATE, q_buf, sdt_buf);
    k_scan2<<<dim3(DINNER/16,BB*NCH,2),256,0,stream>>>(xf_f, xf_b, dtbc_f, dtbc_b, dt_f, dt_b,
        AnF + (size_t)l*DINNER*DSTATE, AnB + (size_t)l*DINNER*DSTATE,
        D_param + (size_t)l*DINNER, D_param_b + (size_t)l*DINNER,
        q_buf, sdt_buf, y_f, y_b);
    k_out<<<dim3(RT),256,0,stream>>>(y_f, y_b, xz, WtOut + (size_t)l*DINNER*DMODEL, residual);
  }
  k_final<<<dim3((NROW+3)/4),256,0,stream>>>(residual, norm_f_w, (float*)d_out);
}